// Round 9
// baseline (562.794 us; speedup 1.0000x reference)
//
#include <hip/hip_runtime.h>

typedef __bf16 bf16x8 __attribute__((ext_vector_type(8)));
typedef float float4v __attribute__((ext_vector_type(4)));
typedef unsigned short ushort4v __attribute__((ext_vector_type(4)));
typedef unsigned short ushort8v __attribute__((ext_vector_type(8)));

#define K_D 512
#define K_S 50

__device__ __forceinline__ float b2f(unsigned short u) {
  union { unsigned int u32; float f; } v; v.u32 = ((unsigned int)u) << 16; return v.f;
}
// Native bf16 cast: compiler packs pairs into v_cvt_pk_bf16_f32 (RNE).
__device__ __forceinline__ unsigned short f2b(float f) {
  __bf16 h = (__bf16)f;
  return __builtin_bit_cast(unsigned short, h);
}

// A/B fragment load from LDS stored [rows][E] bf16, XOR-swizzled (byte ^= (row&7)<<4)
__device__ __forceinline__ bf16x8 ldfrag(const unsigned short* buf, int E, int r0, int k0, int lane) {
  int row = r0 + (lane & 15);
  int kb = (k0 + ((lane >> 4) << 3)) << 1;
  return *(const bf16x8*)(buf + row * E + ((kb ^ ((row & 7) << 4)) >> 1));
}

// Convert fp32 weight W[K][N] (row-major) into fragment-ordered bf16 tiles:
// dst[((nt*KT + kt)*64 + lane)*8 + j] = bf16(W[kt*32 + 8*(lane>>4) + j][nt*16 + (lane&15)])
__global__ void prep_weights(const float* __restrict__ src, unsigned short* __restrict__ dst,
                             int K, int N) {
  int KT = K >> 5;
  int total = (N >> 4) * KT * 64;
  int t = blockIdx.x * blockDim.x + threadIdx.x;
  if (t >= total) return;
  int l = t & 63;
  int kt = (t >> 6) % KT;
  int nt = (t >> 6) / KT;
  int kbase = kt * 32 + ((l >> 4) << 3);
  int col = nt * 16 + (l & 15);
  ushort8v o;
  #pragma unroll
  for (int j = 0; j < 8; ++j) o[j] = f2b(src[(size_t)(kbase + j) * N + col]);
  *(ushort8v*)(dst + (size_t)t * 8) = o;
}

// Wave computes MT m-tiles x NT n-tiles; B fragments prefetched DEPTH kt ahead
// (software pipeline hides L2 weight-load latency). K-loop NOT unrolled.
// All pipeline-array indices are compile-time constant (rule: no dyn-indexed regs).
template<int NT, int KS, int MT, int DEPTH>
__device__ __forceinline__ void mmN(const unsigned short* Ab, int EA,
                                    const bf16x8* __restrict__ Wf, int wnb, int KT, int l,
                                    float4v* acc) {
  bf16x8 bn[NT][DEPTH];
  #pragma unroll
  for (int d = 0; d < DEPTH; ++d) {
    #pragma unroll
    for (int n = 0; n < NT; ++n)
      bn[n][d] = Wf[(size_t)((wnb + n) * KT + d) * 64 + l];
  }
  #pragma unroll 1
  for (int kt = 0; kt < KS; ++kt) {
    bf16x8 bc[NT];
    #pragma unroll
    for (int n = 0; n < NT; ++n) bc[n] = bn[n][0];
    #pragma unroll
    for (int d = 0; d < DEPTH - 1; ++d) {
      #pragma unroll
      for (int n = 0; n < NT; ++n) bn[n][d] = bn[n][d + 1];
    }
    if (kt + DEPTH < KS) {
      #pragma unroll
      for (int n = 0; n < NT; ++n)
        bn[n][DEPTH - 1] = Wf[(size_t)((wnb + n) * KT + kt + DEPTH) * 64 + l];
    }
    bf16x8 a[MT];
    #pragma unroll
    for (int m = 0; m < MT; ++m) a[m] = ldfrag(Ab, EA, m * 16, kt * 32, l);
    #pragma unroll
    for (int n = 0; n < NT; ++n) {
      #pragma unroll
      for (int m = 0; m < MT; ++m)
        acc[m * NT + n] = __builtin_amdgcn_mfma_f32_16x16x32_bf16(a[m], bc[n], acc[m * NT + n], 0, 0, 0);
    }
  }
}

// LayerNorm over rows of sXbuf [64][512] bf16 (swizzled); wave w owns rows 4w..4w+3
__device__ __forceinline__ void ln_pass(unsigned short* sXbuf, const float* __restrict__ g,
                                        const float* __restrict__ bb, int w, int l) {
  float gv[8], bv[8];
  {
    const float4* g4 = (const float4*)(g + l * 8);
    const float4* b4 = (const float4*)(bb + l * 8);
    float4 a0 = g4[0], a1 = g4[1], c0 = b4[0], c1 = b4[1];
    gv[0] = a0.x; gv[1] = a0.y; gv[2] = a0.z; gv[3] = a0.w;
    gv[4] = a1.x; gv[5] = a1.y; gv[6] = a1.z; gv[7] = a1.w;
    bv[0] = c0.x; bv[1] = c0.y; bv[2] = c0.z; bv[3] = c0.w;
    bv[4] = c1.x; bv[5] = c1.y; bv[6] = c1.z; bv[7] = c1.w;
  }
  #pragma unroll 1
  for (int rr = 0; rr < 4; ++rr) {
    int r = (w << 2) + rr;
    int e = r * 512 + (((l << 4) ^ ((r & 7) << 4)) >> 1);  // cols l*8..l*8+7
    ushort8v x = *(const ushort8v*)(sXbuf + e);
    float v[8];
    float s = 0.f, s2 = 0.f;
    #pragma unroll
    for (int j = 0; j < 8; ++j) { v[j] = b2f(x[j]); s += v[j]; s2 += v[j] * v[j]; }
    #pragma unroll
    for (int off = 1; off < 64; off <<= 1) { s += __shfl_xor(s, off); s2 += __shfl_xor(s2, off); }
    float mu = s * (1.f / 512.f);
    float var = s2 * (1.f / 512.f) - mu * mu;
    float rstd = rsqrtf(var + 1e-6f);
    ushort8v o;
    #pragma unroll
    for (int j = 0; j < 8; ++j) o[j] = f2b((v[j] - mu) * rstd * gv[j] + bv[j]);
    *(ushort8v*)(sXbuf + e) = o;
  }
}

// Whole per-block pipeline, templated on MT = number of 16-row tiles actually
// containing valid tokens (rows > len never influence the masked-pooled output;
// rows in (len, 16*MT) are zero-filled so all intermediates stay finite).
template<int MT>
__device__ __forceinline__ void body(
    unsigned short* sX, unsigned short* sQ, unsigned short* sK,
    float* sS, unsigned short* sP,
    const float* __restrict__ embed, const int* __restrict__ gidx,
    const float* __restrict__ b1, const float* __restrict__ b2,
    const float* __restrict__ ln1g, const float* __restrict__ ln1b,
    const float* __restrict__ bqkv, const float* __restrict__ bo,
    const float* __restrict__ ln2g, const float* __restrict__ ln2b,
    const unsigned short* __restrict__ w1f, const unsigned short* __restrict__ w2f,
    const unsigned short* __restrict__ wqkvf, const unsigned short* __restrict__ wof,
    float* __restrict__ out, int tid, int w, int l, int b, int len) {

  // Prefetch depths sized so peak live set stays within the 64-VGPR allocation.
  constexpr int D1 = (MT <= 2) ? 4 : 3;                       // NT=1, KS=16 passes
  constexpr int D2 = (MT <= 2) ? 3 : ((MT == 3) ? 2 : 1);     // NT=2, KS=8 passes
  constexpr int DQ = (MT <= 2) ? 3 : 1;                       // QK fused pass

  // ---- phase 0: embedding gather -> sX rows [0, 16*MT); zeros beyond len ----
  {
    const int sub = tid >> 7;          // 0..7
    const int c0 = (tid & 127) << 2;   // col base
    #pragma unroll 2
    for (int it = 0; it < 2 * MT; ++it) {
      int r = it * 8 + sub;
      float4 v = make_float4(0.f, 0.f, 0.f, 0.f);
      if (r <= len) {
        int row = gidx[b * K_S + r];
        v = *(const float4*)(embed + (size_t)row * K_D + c0);
      }
      ushort4v o;
      o[0] = f2b(v.x); o[1] = f2b(v.y); o[2] = f2b(v.z); o[3] = f2b(v.w);
      *(ushort4v*)(sX + r * 512 + (((c0 << 1) ^ ((r & 7) << 4)) >> 1)) = o;
    }
  }
  __syncthreads();

  // ---- phase 1: F = relu(X @ W1 + b1) -> sQ rows < 16*MT ----
  {
    float4v acc[MT];
    #pragma unroll
    for (int i = 0; i < MT; ++i) acc[i] = (float4v){0.f, 0.f, 0.f, 0.f};
    mmN<1, 16, MT, D1>(sX, 512, (const bf16x8*)w1f, w, 16, l, acc);
    int col = w * 16 + (l & 15);
    float bias = b1[col];
    #pragma unroll
    for (int m = 0; m < MT; ++m) {
      int r0 = m * 16 + ((l >> 4) << 2);
      #pragma unroll
      for (int j = 0; j < 4; ++j) {
        int r = r0 + j;
        float v = fmaxf(acc[m][j] + bias, 0.f);
        sQ[r * 256 + (((col << 1) ^ ((r & 7) << 4)) >> 1)] = f2b(v);
      }
    }
  }
  __syncthreads();

  // ---- phase 2: FF2 = F @ W2 + b2 + X -> sX; then LN1 (rows < 16*MT) ----
  {
    float4v acc[2 * MT];
    #pragma unroll
    for (int i = 0; i < 2 * MT; ++i) acc[i] = (float4v){0.f, 0.f, 0.f, 0.f};
    mmN<2, 8, MT, D2>(sQ, 256, (const bf16x8*)w2f, w * 2, 8, l, acc);
    #pragma unroll
    for (int n = 0; n < 2; ++n) {
      int col = (w * 2 + n) * 16 + (l & 15);
      float bias = b2[col];
      #pragma unroll
      for (int m = 0; m < MT; ++m) {
        int r0 = m * 16 + ((l >> 4) << 2);
        #pragma unroll
        for (int j = 0; j < 4; ++j) {
          int r = r0 + j;
          int e = r * 512 + (((col << 1) ^ ((r & 7) << 4)) >> 1);
          float v = acc[m * 2 + n][j] + bias + b2f(sX[e]);
          sX[e] = f2b(v);
        }
      }
    }
  }
  __syncthreads();
  if (w < 4 * MT) ln_pass(sX, ln1g, ln1b, w, l);
  __syncthreads();

  // ---- phase 3a: Q,K = FF @ Wqkv[:, :512] + bias (one A-pass, DQ-deep prefetch) ----
  {
    const bf16x8* Wf = (const bf16x8*)wqkvf;
    float4v accQ[MT], accK[MT];
    #pragma unroll
    for (int i = 0; i < MT; ++i) {
      accQ[i] = (float4v){0.f, 0.f, 0.f, 0.f};
      accK[i] = (float4v){0.f, 0.f, 0.f, 0.f};
    }
    const size_t baseQ = (size_t)(w) * 16 * 64 + l;
    const size_t baseK = (size_t)(16 + w) * 16 * 64 + l;
    bf16x8 nq[DQ], nk[DQ];
    #pragma unroll
    for (int d = 0; d < DQ; ++d) {
      nq[d] = Wf[baseQ + (size_t)d * 64];
      nk[d] = Wf[baseK + (size_t)d * 64];
    }
    #pragma unroll 1
    for (int kt = 0; kt < 16; ++kt) {
      bf16x8 cq = nq[0], ck = nk[0];
      #pragma unroll
      for (int d = 0; d < DQ - 1; ++d) { nq[d] = nq[d + 1]; nk[d] = nk[d + 1]; }
      if (kt + DQ < 16) {
        nq[DQ - 1] = Wf[baseQ + (size_t)(kt + DQ) * 64];
        nk[DQ - 1] = Wf[baseK + (size_t)(kt + DQ) * 64];
      }
      bf16x8 a[MT];
      #pragma unroll
      for (int m = 0; m < MT; ++m) a[m] = ldfrag(sX, 512, m * 16, kt * 32, l);
      #pragma unroll
      for (int m = 0; m < MT; ++m) accQ[m] = __builtin_amdgcn_mfma_f32_16x16x32_bf16(a[m], cq, accQ[m], 0, 0, 0);
      #pragma unroll
      for (int m = 0; m < MT; ++m) accK[m] = __builtin_amdgcn_mfma_f32_16x16x32_bf16(a[m], ck, accK[m], 0, 0, 0);
    }
    const float qscale = 0.044194173824159216f;  // 1/sqrt(512)
    int col = w * 16 + (l & 15);
    float biasQ = bqkv[col];
    float biasK = bqkv[256 + col];
    #pragma unroll
    for (int m = 0; m < MT; ++m) {
      int r0 = m * 16 + ((l >> 4) << 2);
      #pragma unroll
      for (int j = 0; j < 4; ++j) {
        int r = r0 + j;
        sQ[r * 256 + (((col << 1) ^ ((r & 7) << 4)) >> 1)] = f2b((accQ[m][j] + biasQ) * qscale);
        sK[r * 256 + (((col << 1) ^ ((r & 7) << 4)) >> 1)] = f2b(accK[m][j] + biasK);
      }
    }
  }
  __syncthreads();

  // ---- phase 4 (score-waves) overlapped with phase 3b (V pass, all waves) ----
  if ((w >> 2) < MT) {
    float4v acc = (float4v){0.f, 0.f, 0.f, 0.f};
    int n0 = (w & 3) * 16;
    int m0 = (w >> 2) * 16;
    #pragma unroll
    for (int kt = 0; kt < 8; ++kt) {
      bf16x8 bfr = ldfrag(sK, 256, n0, kt * 32, l);
      bf16x8 a = ldfrag(sQ, 256, m0, kt * 32, l);
      acc = __builtin_amdgcn_mfma_f32_16x16x32_bf16(a, bfr, acc, 0, 0, 0);
    }
    int col = n0 + (l & 15);
    int r0 = m0 + ((l >> 4) << 2);
    #pragma unroll
    for (int j = 0; j < 4; ++j) {
      int r = r0 + j;
      sS[r * 64 + (((col << 2) ^ ((r & 7) << 4)) >> 2)] = acc[j];
    }
  }
  // V = FF @ Wqkv[:, 512:]; V stays in regs until phase 5
  float4v accV[MT];
  {
    #pragma unroll
    for (int i = 0; i < MT; ++i) accV[i] = (float4v){0.f, 0.f, 0.f, 0.f};
    mmN<1, 16, MT, D1>(sX, 512, (const bf16x8*)wqkvf, 32 + w, 16, l, accV);
  }
  __syncthreads();

  // ---- phase 5: masked softmax (rows < 16*MT) -> sP; V^T -> sK (tail zeroed) ----
  {
    if (w < 4 * MT) {
      const bool valid = (l <= len);
      #pragma unroll 1
      for (int rr = 0; rr < 4; ++rr) {
        int r = (w << 2) + rr;
        float s = valid ? sS[r * 64 + (((l << 2) ^ ((r & 7) << 4)) >> 2)] : -1e30f;
        float mx = s;
        #pragma unroll
        for (int off = 1; off < 64; off <<= 1) mx = fmaxf(mx, __shfl_xor(mx, off));
        float p = valid ? __expf(s - mx) : 0.f;
        float sum = p;
        #pragma unroll
        for (int off = 1; off < 64; off <<= 1) sum += __shfl_xor(sum, off);
        sP[r * 64 + (((l << 1) ^ ((r & 7) << 4)) >> 1)] = f2b(p / sum);
      }
    }
    // V^T write (sK free after the phase-4 reads): feature c, rows r0..r0+3.
    // k-rows >= 16*MT zero-filled: P there is 0, but 0 * uninit-LDS-NaN = NaN.
    int c = w * 16 + (l & 15);
    float biasV = bqkv[512 + c];
    #pragma unroll
    for (int m = 0; m < MT; ++m) {
      int r0 = m * 16 + ((l >> 4) << 2);
      ushort4v o;
      #pragma unroll
      for (int j = 0; j < 4; ++j) o[j] = f2b(accV[m][j] + biasV);
      *(ushort4v*)(sK + c * 64 + (((r0 << 1) ^ ((c & 7) << 4)) >> 1)) = o;
    }
    #pragma unroll
    for (int m = MT; m < 4; ++m) {
      int r0 = m * 16 + ((l >> 4) << 2);
      ushort4v o; o[0] = 0; o[1] = 0; o[2] = 0; o[3] = 0;
      *(ushort4v*)(sK + c * 64 + (((r0 << 1) ^ ((c & 7) << 4)) >> 1)) = o;
    }
  }
  __syncthreads();

  // ---- phase 7: ctx = P @ V -> sQ rows < 16*MT ----
  {
    float4v acc[MT];
    #pragma unroll
    for (int i = 0; i < MT; ++i) acc[i] = (float4v){0.f, 0.f, 0.f, 0.f};
    #pragma unroll
    for (int kt = 0; kt < 2; ++kt) {
      bf16x8 bfr = ldfrag(sK, 64, w * 16, kt * 32, l);
      #pragma unroll
      for (int m = 0; m < MT; ++m) {
        bf16x8 a = ldfrag(sP, 64, m * 16, kt * 32, l);
        acc[m] = __builtin_amdgcn_mfma_f32_16x16x32_bf16(a, bfr, acc[m], 0, 0, 0);
      }
    }
    int col = w * 16 + (l & 15);
    #pragma unroll
    for (int m = 0; m < MT; ++m) {
      int r0 = m * 16 + ((l >> 4) << 2);
      #pragma unroll
      for (int j = 0; j < 4; ++j) {
        int r = r0 + j;
        sQ[r * 256 + (((col << 1) ^ ((r & 7) << 4)) >> 1)] = f2b(acc[m][j]);
      }
    }
  }
  __syncthreads();

  // ---- phase 8: O = ctx @ Wo + bo + FF -> sX; LN2 (rows < 16*MT) ----
  {
    float4v acc[2 * MT];
    #pragma unroll
    for (int i = 0; i < 2 * MT; ++i) acc[i] = (float4v){0.f, 0.f, 0.f, 0.f};
    mmN<2, 8, MT, D2>(sQ, 256, (const bf16x8*)wof, w * 2, 8, l, acc);
    #pragma unroll
    for (int n = 0; n < 2; ++n) {
      int col = (w * 2 + n) * 16 + (l & 15);
      float bias = bo[col];
      #pragma unroll
      for (int m = 0; m < MT; ++m) {
        int r0 = m * 16 + ((l >> 4) << 2);
        #pragma unroll
        for (int j = 0; j < 4; ++j) {
          int r = r0 + j;
          int e = r * 512 + (((col << 1) ^ ((r & 7) << 4)) >> 1);
          float v = acc[m * 2 + n][j] + bias + b2f(sX[e]);
          sX[e] = f2b(v);
        }
      }
    }
  }
  __syncthreads();
  if (w < 4 * MT) ln_pass(sX, ln2g, ln2b, w, l);
  __syncthreads();

  // ---- phase 9: masked mean pool -> out[b][512]; two row-halves via sS scratch ----
  {
    int col = tid & 511;
    int half = tid >> 9;  // 0 or 1
    float sum = 0.f;
    for (int s = half; s <= len; s += 2)
      sum += b2f(sX[s * 512 + (((col << 1) ^ ((s & 7) << 4)) >> 1)]);
    if (half) sS[col] = sum;
    __syncthreads();
    if (!half) out[(size_t)b * K_D + col] = (sum + sS[col]) / (float)(len + 1);
  }
}

__global__ __launch_bounds__(1024, 4)
void fused_block(
    const float* __restrict__ embed, const int* __restrict__ gidx,
    const int* __restrict__ lengths,
    const float* __restrict__ b1, const float* __restrict__ b2,
    const float* __restrict__ ln1g, const float* __restrict__ ln1b,
    const float* __restrict__ bqkv, const float* __restrict__ bo,
    const float* __restrict__ ln2g, const float* __restrict__ ln2b,
    const unsigned short* __restrict__ w1f, const unsigned short* __restrict__ w2f,
    const unsigned short* __restrict__ wqkvf, const unsigned short* __restrict__ wof,
    float* __restrict__ out) {
  __shared__ unsigned short sX[64 * 512];  // X, then FF(post-LN1), then LN2 out
  __shared__ unsigned short sQ[64 * 256];  // F, then Q, then ctx
  __shared__ unsigned short sK[64 * 256];  // K, then V^T [256][64]
  __shared__ float sS[64 * 64];            // raw scores fp32; later pool scratch
  __shared__ unsigned short sP[64 * 64];   // probs bf16

  const int tid = (int)threadIdx.x;
  const int w = tid >> 6;   // 0..15
  const int l = tid & 63;
  const int b = (int)blockIdx.x;
  const int len = lengths[b];
  const int mt = (len + 16) >> 4;  // ceil((len+1)/16), 1..4

  switch (mt) {
    case 1: body<1>(sX, sQ, sK, sS, sP, embed, gidx, b1, b2, ln1g, ln1b, bqkv, bo,
                    ln2g, ln2b, w1f, w2f, wqkvf, wof, out, tid, w, l, b, len); break;
    case 2: body<2>(sX, sQ, sK, sS, sP, embed, gidx, b1, b2, ln1g, ln1b, bqkv, bo,
                    ln2g, ln2b, w1f, w2f, wqkvf, wof, out, tid, w, l, b, len); break;
    case 3: body<3>(sX, sQ, sK, sS, sP, embed, gidx, b1, b2, ln1g, ln1b, bqkv, bo,
                    ln2g, ln2b, w1f, w2f, wqkvf, wof, out, tid, w, l, b, len); break;
    default: body<4>(sX, sQ, sK, sS, sP, embed, gidx, b1, b2, ln1g, ln1b, bqkv, bo,
                     ln2g, ln2b, w1f, w2f, wqkvf, wof, out, tid, w, l, b, len); break;
  }
}

extern "C" void kernel_launch(void* const* d_in, const int* in_sizes, int n_in,
                              void* d_out, int out_size, void* d_ws, size_t ws_size,
                              hipStream_t stream) {
  (void)in_sizes; (void)n_in; (void)out_size; (void)ws_size;
  const float* embed = (const float*)d_in[0];
  const int* idx = (const int*)d_in[1];
  const int* lengths = (const int*)d_in[2];
  const float* W1 = (const float*)d_in[3];
  const float* b1 = (const float*)d_in[4];
  const float* W2 = (const float*)d_in[5];
  const float* b2 = (const float*)d_in[6];
  const float* ln1g = (const float*)d_in[7];
  const float* ln1b = (const float*)d_in[8];
  const float* Wqkv = (const float*)d_in[9];
  const float* bqkv = (const float*)d_in[10];
  const float* Wo = (const float*)d_in[11];
  const float* bo = (const float*)d_in[12];
  const float* ln2g = (const float*)d_in[13];
  const float* ln2b = (const float*)d_in[14];

  unsigned short* ws = (unsigned short*)d_ws;
  unsigned short* w1f = ws;                 // 16 nt * 16 kt * 512  = 131072 bf16
  unsigned short* w2f = ws + 131072;        // 32 nt *  8 kt * 512  = 131072
  unsigned short* wqkvf = ws + 262144;      // 48 nt * 16 kt * 512  = 393216
  unsigned short* wof = ws + 655360;        // 32 nt *  8 kt * 512  = 131072

  prep_weights<<<64, 256, 0, stream>>>(W1, w1f, 512, 256);
  prep_weights<<<64, 256, 0, stream>>>(W2, w2f, 256, 512);
  prep_weights<<<192, 256, 0, stream>>>(Wqkv, wqkvf, 512, 768);
  prep_weights<<<64, 256, 0, stream>>>(Wo, wof, 256, 512);

  fused_block<<<4096, 1024, 0, stream>>>(embed, idx, lengths, b1, b2, ln1g, ln1b,
                                         bqkv, bo, ln2g, ln2b, w1f, w2f, wqkvf, wof,
                                         (float*)d_out);
}

// Round 10
// 528.288 us; speedup vs baseline: 1.0653x; 1.0653x over previous
//
#include <hip/hip_runtime.h>

typedef __bf16 bf16x8 __attribute__((ext_vector_type(8)));
typedef float float4v __attribute__((ext_vector_type(4)));
typedef unsigned short ushort4v __attribute__((ext_vector_type(4)));
typedef unsigned short ushort8v __attribute__((ext_vector_type(8)));

#define K_D 512
#define K_S 50

__device__ __forceinline__ float b2f(unsigned short u) {
  union { unsigned int u32; float f; } v; v.u32 = ((unsigned int)u) << 16; return v.f;
}
// Native bf16 cast: compiler packs pairs into v_cvt_pk_bf16_f32 (RNE).
__device__ __forceinline__ unsigned short f2b(float f) {
  __bf16 h = (__bf16)f;
  return __builtin_bit_cast(unsigned short, h);
}

// A/B fragment load from LDS stored [rows][E] bf16, XOR-swizzled (byte ^= (row&7)<<4)
__device__ __forceinline__ bf16x8 ldfrag(const unsigned short* buf, int E, int r0, int k0, int lane) {
  int row = r0 + (lane & 15);
  int kb = (k0 + ((lane >> 4) << 3)) << 1;
  return *(const bf16x8*)(buf + row * E + ((kb ^ ((row & 7) << 4)) >> 1));
}

// Convert fp32 weight W[K][N] (row-major) into fragment-ordered bf16 tiles:
// dst[((nt*KT + kt)*64 + lane)*8 + j] = bf16(W[kt*32 + 8*(lane>>4) + j][nt*16 + (lane&15)])
__global__ void prep_weights(const float* __restrict__ src, unsigned short* __restrict__ dst,
                             int K, int N) {
  int KT = K >> 5;
  int total = (N >> 4) * KT * 64;
  int t = blockIdx.x * blockDim.x + threadIdx.x;
  if (t >= total) return;
  int l = t & 63;
  int kt = (t >> 6) % KT;
  int nt = (t >> 6) / KT;
  int kbase = kt * 32 + ((l >> 4) << 3);
  int col = nt * 16 + (l & 15);
  ushort8v o;
  #pragma unroll
  for (int j = 0; j < 8; ++j) o[j] = f2b(src[(size_t)(kbase + j) * N + col]);
  *(ushort8v*)(dst + (size_t)t * 8) = o;
}

// Wave computes MT m-tiles x NT n-tiles.
// SLOTS=2: kt unrolled by 2 with two in-place prefetch slots; each slot is
// consumed by its MFMA and THEN refilled (no WAR copy, no register shifting).
// SLOTS=1: single slot, same consume-then-refill discipline.
template<int NT, int KS, int MT, int SLOTS>
__device__ __forceinline__ void mmN(const unsigned short* Ab, int EA,
                                    const bf16x8* __restrict__ Wf, int wnb, int KT, int l,
                                    float4v* acc) {
  if constexpr (SLOTS == 2) {
    bf16x8 p0[NT], p1[NT];
    #pragma unroll
    for (int n = 0; n < NT; ++n) {
      p0[n] = Wf[(size_t)((wnb + n) * KT) * 64 + l];
      p1[n] = Wf[(size_t)((wnb + n) * KT + 1) * 64 + l];
    }
    #pragma unroll 1
    for (int kt = 0; kt < KS; kt += 2) {
      {
        bf16x8 a[MT];
        #pragma unroll
        for (int m = 0; m < MT; ++m) a[m] = ldfrag(Ab, EA, m * 16, kt * 32, l);
        #pragma unroll
        for (int n = 0; n < NT; ++n) {
          #pragma unroll
          for (int m = 0; m < MT; ++m)
            acc[m * NT + n] = __builtin_amdgcn_mfma_f32_16x16x32_bf16(a[m], p0[n], acc[m * NT + n], 0, 0, 0);
        }
        if (kt + 2 < KS) {
          #pragma unroll
          for (int n = 0; n < NT; ++n)
            p0[n] = Wf[(size_t)((wnb + n) * KT + kt + 2) * 64 + l];
        }
      }
      {
        bf16x8 a[MT];
        #pragma unroll
        for (int m = 0; m < MT; ++m) a[m] = ldfrag(Ab, EA, m * 16, (kt + 1) * 32, l);
        #pragma unroll
        for (int n = 0; n < NT; ++n) {
          #pragma unroll
          for (int m = 0; m < MT; ++m)
            acc[m * NT + n] = __builtin_amdgcn_mfma_f32_16x16x32_bf16(a[m], p1[n], acc[m * NT + n], 0, 0, 0);
        }
        if (kt + 3 < KS) {
          #pragma unroll
          for (int n = 0; n < NT; ++n)
            p1[n] = Wf[(size_t)((wnb + n) * KT + kt + 3) * 64 + l];
        }
      }
    }
  } else {
    bf16x8 bn[NT];
    #pragma unroll
    for (int n = 0; n < NT; ++n) bn[n] = Wf[(size_t)((wnb + n) * KT) * 64 + l];
    #pragma unroll 1
    for (int kt = 0; kt < KS; ++kt) {
      bf16x8 a[MT];
      #pragma unroll
      for (int m = 0; m < MT; ++m) a[m] = ldfrag(Ab, EA, m * 16, kt * 32, l);
      #pragma unroll
      for (int n = 0; n < NT; ++n) {
        #pragma unroll
        for (int m = 0; m < MT; ++m)
          acc[m * NT + n] = __builtin_amdgcn_mfma_f32_16x16x32_bf16(a[m], bn[n], acc[m * NT + n], 0, 0, 0);
      }
      if (kt + 1 < KS) {
        #pragma unroll
        for (int n = 0; n < NT; ++n)
          bn[n] = Wf[(size_t)((wnb + n) * KT + kt + 1) * 64 + l];
      }
    }
  }
}

// LayerNorm over rows of sXbuf [64][512] bf16 (swizzled); wave w owns rows 4w..4w+3
__device__ __forceinline__ void ln_pass(unsigned short* sXbuf, const float* __restrict__ g,
                                        const float* __restrict__ bb, int w, int l) {
  float gv[8], bv[8];
  {
    const float4* g4 = (const float4*)(g + l * 8);
    const float4* b4 = (const float4*)(bb + l * 8);
    float4 a0 = g4[0], a1 = g4[1], c0 = b4[0], c1 = b4[1];
    gv[0] = a0.x; gv[1] = a0.y; gv[2] = a0.z; gv[3] = a0.w;
    gv[4] = a1.x; gv[5] = a1.y; gv[6] = a1.z; gv[7] = a1.w;
    bv[0] = c0.x; bv[1] = c0.y; bv[2] = c0.z; bv[3] = c0.w;
    bv[4] = c1.x; bv[5] = c1.y; bv[6] = c1.z; bv[7] = c1.w;
  }
  #pragma unroll 1
  for (int rr = 0; rr < 4; ++rr) {
    int r = (w << 2) + rr;
    int e = r * 512 + (((l << 4) ^ ((r & 7) << 4)) >> 1);  // cols l*8..l*8+7
    ushort8v x = *(const ushort8v*)(sXbuf + e);
    float v[8];
    float s = 0.f, s2 = 0.f;
    #pragma unroll
    for (int j = 0; j < 8; ++j) { v[j] = b2f(x[j]); s += v[j]; s2 += v[j] * v[j]; }
    #pragma unroll
    for (int off = 1; off < 64; off <<= 1) { s += __shfl_xor(s, off); s2 += __shfl_xor(s2, off); }
    float mu = s * (1.f / 512.f);
    float var = s2 * (1.f / 512.f) - mu * mu;
    float rstd = rsqrtf(var + 1e-6f);
    ushort8v o;
    #pragma unroll
    for (int j = 0; j < 8; ++j) o[j] = f2b((v[j] - mu) * rstd * gv[j] + bv[j]);
    *(ushort8v*)(sXbuf + e) = o;
  }
}

// Whole per-block pipeline, templated on MT = number of 16-row tiles actually
// containing valid tokens (rows > len never influence the masked-pooled output;
// rows in (len, 16*MT) are zero-filled so all intermediates stay finite).
template<int MT>
__device__ __forceinline__ void body(
    unsigned short* sX, unsigned short* sQ, unsigned short* sK,
    float* sS, unsigned short* sP,
    const float* __restrict__ embed, const int* __restrict__ gidx,
    const float* __restrict__ b1, const float* __restrict__ b2,
    const float* __restrict__ ln1g, const float* __restrict__ ln1b,
    const float* __restrict__ bqkv, const float* __restrict__ bo,
    const float* __restrict__ ln2g, const float* __restrict__ ln2b,
    const unsigned short* __restrict__ w1f, const unsigned short* __restrict__ w2f,
    const unsigned short* __restrict__ wqkvf, const unsigned short* __restrict__ wof,
    float* __restrict__ out, int tid, int w, int l, int b, int len) {

  // Slot counts sized so peak live set stays within the 64-VGPR allocation.
  constexpr int S2 = (MT <= 3) ? 2 : 1;   // NT=2 (FF2, Wo) passes

  // ---- phase 0: embedding gather -> sX rows [0, 16*MT); zeros beyond len ----
  {
    const int sub = tid >> 7;          // 0..7
    const int c0 = (tid & 127) << 2;   // col base
    #pragma unroll 2
    for (int it = 0; it < 2 * MT; ++it) {
      int r = it * 8 + sub;
      float4 v = make_float4(0.f, 0.f, 0.f, 0.f);
      if (r <= len) {
        int row = gidx[b * K_S + r];
        v = *(const float4*)(embed + (size_t)row * K_D + c0);
      }
      ushort4v o;
      o[0] = f2b(v.x); o[1] = f2b(v.y); o[2] = f2b(v.z); o[3] = f2b(v.w);
      *(ushort4v*)(sX + r * 512 + (((c0 << 1) ^ ((r & 7) << 4)) >> 1)) = o;
    }
  }
  __syncthreads();

  // ---- phase 1: F = relu(X @ W1 + b1) -> sQ rows < 16*MT ----
  {
    float4v acc[MT];
    #pragma unroll
    for (int i = 0; i < MT; ++i) acc[i] = (float4v){0.f, 0.f, 0.f, 0.f};
    mmN<1, 16, MT, 2>(sX, 512, (const bf16x8*)w1f, w, 16, l, acc);
    int col = w * 16 + (l & 15);
    float bias = b1[col];
    #pragma unroll
    for (int m = 0; m < MT; ++m) {
      int r0 = m * 16 + ((l >> 4) << 2);
      #pragma unroll
      for (int j = 0; j < 4; ++j) {
        int r = r0 + j;
        float v = fmaxf(acc[m][j] + bias, 0.f);
        sQ[r * 256 + (((col << 1) ^ ((r & 7) << 4)) >> 1)] = f2b(v);
      }
    }
  }
  __syncthreads();

  // ---- phase 2: FF2 = F @ W2 + b2 + X -> sX; then LN1 (rows < 16*MT) ----
  {
    float4v acc[2 * MT];
    #pragma unroll
    for (int i = 0; i < 2 * MT; ++i) acc[i] = (float4v){0.f, 0.f, 0.f, 0.f};
    mmN<2, 8, MT, S2>(sQ, 256, (const bf16x8*)w2f, w * 2, 8, l, acc);
    #pragma unroll
    for (int n = 0; n < 2; ++n) {
      int col = (w * 2 + n) * 16 + (l & 15);
      float bias = b2[col];
      #pragma unroll
      for (int m = 0; m < MT; ++m) {
        int r0 = m * 16 + ((l >> 4) << 2);
        #pragma unroll
        for (int j = 0; j < 4; ++j) {
          int r = r0 + j;
          int e = r * 512 + (((col << 1) ^ ((r & 7) << 4)) >> 1);
          float v = acc[m * 2 + n][j] + bias + b2f(sX[e]);
          sX[e] = f2b(v);
        }
      }
    }
  }
  __syncthreads();
  if (w < 4 * MT) ln_pass(sX, ln1g, ln1b, w, l);
  __syncthreads();

  // ---- phase 3a: Q,K = FF @ Wqkv[:, :512] + bias (one A-pass) ----
  {
    const bf16x8* Wf = (const bf16x8*)wqkvf;
    float4v accQ[MT], accK[MT];
    #pragma unroll
    for (int i = 0; i < MT; ++i) {
      accQ[i] = (float4v){0.f, 0.f, 0.f, 0.f};
      accK[i] = (float4v){0.f, 0.f, 0.f, 0.f};
    }
    const size_t baseQ = (size_t)(w) * 16 * 64 + l;
    const size_t baseK = (size_t)(16 + w) * 16 * 64 + l;
    if constexpr (MT <= 2) {
      // two-slot, unroll-2, consume-then-refill (no copies)
      bf16x8 q0 = Wf[baseQ],       k0 = Wf[baseK];
      bf16x8 q1 = Wf[baseQ + 64],  k1 = Wf[baseK + 64];
      #pragma unroll 1
      for (int kt = 0; kt < 16; kt += 2) {
        {
          bf16x8 a[MT];
          #pragma unroll
          for (int m = 0; m < MT; ++m) a[m] = ldfrag(sX, 512, m * 16, kt * 32, l);
          #pragma unroll
          for (int m = 0; m < MT; ++m) accQ[m] = __builtin_amdgcn_mfma_f32_16x16x32_bf16(a[m], q0, accQ[m], 0, 0, 0);
          #pragma unroll
          for (int m = 0; m < MT; ++m) accK[m] = __builtin_amdgcn_mfma_f32_16x16x32_bf16(a[m], k0, accK[m], 0, 0, 0);
          if (kt + 2 < 16) {
            q0 = Wf[baseQ + (size_t)(kt + 2) * 64];
            k0 = Wf[baseK + (size_t)(kt + 2) * 64];
          }
        }
        {
          bf16x8 a[MT];
          #pragma unroll
          for (int m = 0; m < MT; ++m) a[m] = ldfrag(sX, 512, m * 16, (kt + 1) * 32, l);
          #pragma unroll
          for (int m = 0; m < MT; ++m) accQ[m] = __builtin_amdgcn_mfma_f32_16x16x32_bf16(a[m], q1, accQ[m], 0, 0, 0);
          #pragma unroll
          for (int m = 0; m < MT; ++m) accK[m] = __builtin_amdgcn_mfma_f32_16x16x32_bf16(a[m], k1, accK[m], 0, 0, 0);
          if (kt + 3 < 16) {
            q1 = Wf[baseQ + (size_t)(kt + 3) * 64];
            k1 = Wf[baseK + (size_t)(kt + 3) * 64];
          }
        }
      }
    } else {
      bf16x8 q0 = Wf[baseQ], k0 = Wf[baseK];
      #pragma unroll 1
      for (int kt = 0; kt < 16; ++kt) {
        bf16x8 a[MT];
        #pragma unroll
        for (int m = 0; m < MT; ++m) a[m] = ldfrag(sX, 512, m * 16, kt * 32, l);
        #pragma unroll
        for (int m = 0; m < MT; ++m) accQ[m] = __builtin_amdgcn_mfma_f32_16x16x32_bf16(a[m], q0, accQ[m], 0, 0, 0);
        #pragma unroll
        for (int m = 0; m < MT; ++m) accK[m] = __builtin_amdgcn_mfma_f32_16x16x32_bf16(a[m], k0, accK[m], 0, 0, 0);
        if (kt + 1 < 16) {
          q0 = Wf[baseQ + (size_t)(kt + 1) * 64];
          k0 = Wf[baseK + (size_t)(kt + 1) * 64];
        }
      }
    }
    const float qscale = 0.044194173824159216f;  // 1/sqrt(512)
    int col = w * 16 + (l & 15);
    float biasQ = bqkv[col];
    float biasK = bqkv[256 + col];
    #pragma unroll
    for (int m = 0; m < MT; ++m) {
      int r0 = m * 16 + ((l >> 4) << 2);
      #pragma unroll
      for (int j = 0; j < 4; ++j) {
        int r = r0 + j;
        sQ[r * 256 + (((col << 1) ^ ((r & 7) << 4)) >> 1)] = f2b((accQ[m][j] + biasQ) * qscale);
        sK[r * 256 + (((col << 1) ^ ((r & 7) << 4)) >> 1)] = f2b(accK[m][j] + biasK);
      }
    }
  }
  __syncthreads();

  // ---- phase 4 (score-waves) overlapped with phase 3b (V pass, all waves) ----
  if ((w >> 2) < MT) {
    float4v acc = (float4v){0.f, 0.f, 0.f, 0.f};
    int n0 = (w & 3) * 16;
    int m0 = (w >> 2) * 16;
    #pragma unroll
    for (int kt = 0; kt < 8; ++kt) {
      bf16x8 bfr = ldfrag(sK, 256, n0, kt * 32, l);
      bf16x8 a = ldfrag(sQ, 256, m0, kt * 32, l);
      acc = __builtin_amdgcn_mfma_f32_16x16x32_bf16(a, bfr, acc, 0, 0, 0);
    }
    int col = n0 + (l & 15);
    int r0 = m0 + ((l >> 4) << 2);
    #pragma unroll
    for (int j = 0; j < 4; ++j) {
      int r = r0 + j;
      sS[r * 64 + (((col << 2) ^ ((r & 7) << 4)) >> 2)] = acc[j];
    }
  }
  // V = FF @ Wqkv[:, 512:]; V stays in regs until phase 5
  float4v accV[MT];
  {
    #pragma unroll
    for (int i = 0; i < MT; ++i) accV[i] = (float4v){0.f, 0.f, 0.f, 0.f};
    mmN<1, 16, MT, 2>(sX, 512, (const bf16x8*)wqkvf, 32 + w, 16, l, accV);
  }
  __syncthreads();

  // ---- phase 5: masked softmax (rows < 16*MT) -> sP; V^T -> sK (tail zeroed) ----
  {
    if (w < 4 * MT) {
      const bool valid = (l <= len);
      #pragma unroll 1
      for (int rr = 0; rr < 4; ++rr) {
        int r = (w << 2) + rr;
        float s = valid ? sS[r * 64 + (((l << 2) ^ ((r & 7) << 4)) >> 2)] : -1e30f;
        float mx = s;
        #pragma unroll
        for (int off = 1; off < 64; off <<= 1) mx = fmaxf(mx, __shfl_xor(mx, off));
        float p = valid ? __expf(s - mx) : 0.f;
        float sum = p;
        #pragma unroll
        for (int off = 1; off < 64; off <<= 1) sum += __shfl_xor(sum, off);
        sP[r * 64 + (((l << 1) ^ ((r & 7) << 4)) >> 1)] = f2b(p / sum);
      }
    }
    // V^T write (sK free after the phase-4 reads): feature c, rows r0..r0+3.
    // k-rows >= 16*MT zero-filled: P there is 0, but 0 * uninit-LDS-NaN = NaN.
    int c = w * 16 + (l & 15);
    float biasV = bqkv[512 + c];
    #pragma unroll
    for (int m = 0; m < MT; ++m) {
      int r0 = m * 16 + ((l >> 4) << 2);
      ushort4v o;
      #pragma unroll
      for (int j = 0; j < 4; ++j) o[j] = f2b(accV[m][j] + biasV);
      *(ushort4v*)(sK + c * 64 + (((r0 << 1) ^ ((c & 7) << 4)) >> 1)) = o;
    }
    #pragma unroll
    for (int m = MT; m < 4; ++m) {
      int r0 = m * 16 + ((l >> 4) << 2);
      ushort4v o; o[0] = 0; o[1] = 0; o[2] = 0; o[3] = 0;
      *(ushort4v*)(sK + c * 64 + (((r0 << 1) ^ ((c & 7) << 4)) >> 1)) = o;
    }
  }
  __syncthreads();

  // ---- phase 7: ctx = P @ V -> sQ rows < 16*MT ----
  {
    float4v acc[MT];
    #pragma unroll
    for (int i = 0; i < MT; ++i) acc[i] = (float4v){0.f, 0.f, 0.f, 0.f};
    #pragma unroll
    for (int kt = 0; kt < 2; ++kt) {
      bf16x8 bfr = ldfrag(sK, 64, w * 16, kt * 32, l);
      #pragma unroll
      for (int m = 0; m < MT; ++m) {
        bf16x8 a = ldfrag(sP, 64, m * 16, kt * 32, l);
        acc[m] = __builtin_amdgcn_mfma_f32_16x16x32_bf16(a, bfr, acc[m], 0, 0, 0);
      }
    }
    int col = w * 16 + (l & 15);
    #pragma unroll
    for (int m = 0; m < MT; ++m) {
      int r0 = m * 16 + ((l >> 4) << 2);
      #pragma unroll
      for (int j = 0; j < 4; ++j) {
        int r = r0 + j;
        sQ[r * 256 + (((col << 1) ^ ((r & 7) << 4)) >> 1)] = f2b(acc[m][j]);
      }
    }
  }
  __syncthreads();

  // ---- phase 8: O = ctx @ Wo + bo + FF -> sX; LN2 (rows < 16*MT) ----
  {
    float4v acc[2 * MT];
    #pragma unroll
    for (int i = 0; i < 2 * MT; ++i) acc[i] = (float4v){0.f, 0.f, 0.f, 0.f};
    mmN<2, 8, MT, S2>(sQ, 256, (const bf16x8*)wof, w * 2, 8, l, acc);
    #pragma unroll
    for (int n = 0; n < 2; ++n) {
      int col = (w * 2 + n) * 16 + (l & 15);
      float bias = bo[col];
      #pragma unroll
      for (int m = 0; m < MT; ++m) {
        int r0 = m * 16 + ((l >> 4) << 2);
        #pragma unroll
        for (int j = 0; j < 4; ++j) {
          int r = r0 + j;
          int e = r * 512 + (((col << 1) ^ ((r & 7) << 4)) >> 1);
          float v = acc[m * 2 + n][j] + bias + b2f(sX[e]);
          sX[e] = f2b(v);
        }
      }
    }
  }
  __syncthreads();
  if (w < 4 * MT) ln_pass(sX, ln2g, ln2b, w, l);
  __syncthreads();

  // ---- phase 9: masked mean pool -> out[b][512]; two row-halves via sS scratch ----
  {
    int col = tid & 511;
    int half = tid >> 9;  // 0 or 1
    float sum = 0.f;
    for (int s = half; s <= len; s += 2)
      sum += b2f(sX[s * 512 + (((col << 1) ^ ((s & 7) << 4)) >> 1)]);
    if (half) sS[col] = sum;
    __syncthreads();
    if (!half) out[(size_t)b * K_D + col] = (sum + sS[col]) / (float)(len + 1);
  }
}

__global__ __launch_bounds__(1024, 4)
void fused_block(
    const float* __restrict__ embed, const int* __restrict__ gidx,
    const int* __restrict__ lengths,
    const float* __restrict__ b1, const float* __restrict__ b2,
    const float* __restrict__ ln1g, const float* __restrict__ ln1b,
    const float* __restrict__ bqkv, const float* __restrict__ bo,
    const float* __restrict__ ln2g, const float* __restrict__ ln2b,
    const unsigned short* __restrict__ w1f, const unsigned short* __restrict__ w2f,
    const unsigned short* __restrict__ wqkvf, const unsigned short* __restrict__ wof,
    float* __restrict__ out) {
  __shared__ unsigned short sX[64 * 512];  // X, then FF(post-LN1), then LN2 out
  __shared__ unsigned short sQ[64 * 256];  // F, then Q, then ctx
  __shared__ unsigned short sK[64 * 256];  // K, then V^T [256][64]
  __shared__ float sS[64 * 64];            // raw scores fp32; later pool scratch
  __shared__ unsigned short sP[64 * 64];   // probs bf16

  const int tid = (int)threadIdx.x;
  const int w = tid >> 6;   // 0..15
  const int l = tid & 63;
  const int b = (int)blockIdx.x;
  const int len = lengths[b];
  const int mt = (len + 16) >> 4;  // ceil((len+1)/16), 1..4

  switch (mt) {
    case 1: body<1>(sX, sQ, sK, sS, sP, embed, gidx, b1, b2, ln1g, ln1b, bqkv, bo,
                    ln2g, ln2b, w1f, w2f, wqkvf, wof, out, tid, w, l, b, len); break;
    case 2: body<2>(sX, sQ, sK, sS, sP, embed, gidx, b1, b2, ln1g, ln1b, bqkv, bo,
                    ln2g, ln2b, w1f, w2f, wqkvf, wof, out, tid, w, l, b, len); break;
    case 3: body<3>(sX, sQ, sK, sS, sP, embed, gidx, b1, b2, ln1g, ln1b, bqkv, bo,
                    ln2g, ln2b, w1f, w2f, wqkvf, wof, out, tid, w, l, b, len); break;
    default: body<4>(sX, sQ, sK, sS, sP, embed, gidx, b1, b2, ln1g, ln1b, bqkv, bo,
                     ln2g, ln2b, w1f, w2f, wqkvf, wof, out, tid, w, l, b, len); break;
  }
}

extern "C" void kernel_launch(void* const* d_in, const int* in_sizes, int n_in,
                              void* d_out, int out_size, void* d_ws, size_t ws_size,
                              hipStream_t stream) {
  (void)in_sizes; (void)n_in; (void)out_size; (void)ws_size;
  const float* embed = (const float*)d_in[0];
  const int* idx = (const int*)d_in[1];
  const int* lengths = (const int*)d_in[2];
  const float* W1 = (const float*)d_in[3];
  const float* b1 = (const float*)d_in[4];
  const float* W2 = (const float*)d_in[5];
  const float* b2 = (const float*)d_in[6];
  const float* ln1g = (const float*)d_in[7];
  const float* ln1b = (const float*)d_in[8];
  const float* Wqkv = (const float*)d_in[9];
  const float* bqkv = (const float*)d_in[10];
  const float* Wo = (const float*)d_in[11];
  const float* bo = (const float*)d_in[12];
  const float* ln2g = (const float*)d_in[13];
  const float* ln2b = (const float*)d_in[14];

  unsigned short* ws = (unsigned short*)d_ws;
  unsigned short* w1f = ws;                 // 16 nt * 16 kt * 512  = 131072 bf16
  unsigned short* w2f = ws + 131072;        // 32 nt *  8 kt * 512  = 131072
  unsigned short* wqkvf = ws + 262144;      // 48 nt * 16 kt * 512  = 393216
  unsigned short* wof = ws + 655360;        // 32 nt *  8 kt * 512  = 131072

  prep_weights<<<64, 256, 0, stream>>>(W1, w1f, 512, 256);
  prep_weights<<<64, 256, 0, stream>>>(W2, w2f, 256, 512);
  prep_weights<<<192, 256, 0, stream>>>(Wqkv, wqkvf, 512, 768);
  prep_weights<<<64, 256, 0, stream>>>(Wo, wof, 256, 512);

  fused_block<<<4096, 1024, 0, stream>>>(embed, idx, lengths, b1, b2, ln1g, ln1b,
                                         bqkv, bo, ln2g, ln2b, w1f, w2f, wqkvf, wof,
                                         (float*)d_out);
}

// Round 11
// 512.038 us; speedup vs baseline: 1.0991x; 1.0317x over previous
//
#include <hip/hip_runtime.h>

typedef __bf16 bf16x8 __attribute__((ext_vector_type(8)));
typedef float float4v __attribute__((ext_vector_type(4)));
typedef unsigned short ushort4v __attribute__((ext_vector_type(4)));
typedef unsigned short ushort8v __attribute__((ext_vector_type(8)));

#define K_D 512
#define K_S 50

__device__ __forceinline__ float b2f(unsigned short u) {
  union { unsigned int u32; float f; } v; v.u32 = ((unsigned int)u) << 16; return v.f;
}
// Native bf16 cast: compiler packs pairs into v_cvt_pk_bf16_f32 (RNE).
__device__ __forceinline__ unsigned short f2b(float f) {
  __bf16 h = (__bf16)f;
  return __builtin_bit_cast(unsigned short, h);
}

// A/B fragment load from LDS stored [rows][E] bf16, XOR-swizzled (byte ^= (row&7)<<4)
__device__ __forceinline__ bf16x8 ldfrag(const unsigned short* buf, int E, int r0, int k0, int lane) {
  int row = r0 + (lane & 15);
  int kb = (k0 + ((lane >> 4) << 3)) << 1;
  return *(const bf16x8*)(buf + row * E + ((kb ^ ((row & 7) << 4)) >> 1));
}

// Convert fp32 weight W[K][N] (row-major) into fragment-ordered bf16 tiles:
// dst[((nt*KT + kt)*64 + lane)*8 + j] = bf16(W[kt*32 + 8*(lane>>4) + j][nt*16 + (lane&15)])
__global__ void prep_weights(const float* __restrict__ src, unsigned short* __restrict__ dst,
                             int K, int N) {
  int KT = K >> 5;
  int total = (N >> 4) * KT * 64;
  int t = blockIdx.x * blockDim.x + threadIdx.x;
  if (t >= total) return;
  int l = t & 63;
  int kt = (t >> 6) % KT;
  int nt = (t >> 6) / KT;
  int kbase = kt * 32 + ((l >> 4) << 3);
  int col = nt * 16 + (l & 15);
  ushort8v o;
  #pragma unroll
  for (int j = 0; j < 8; ++j) o[j] = f2b(src[(size_t)(kbase + j) * N + col]);
  *(ushort8v*)(dst + (size_t)t * 8) = o;
}

// Wave computes MT m-tiles x NT n-tiles.
// SLOTS=2: kt unrolled by 2 with two in-place B prefetch slots (consume-then-
// refill, no copies). APRE=1 additionally double-slots the A (LDS) fragments,
// refilled right after their MFMAs -> ~2 sub-blocks of slack hides ds_read
// latency. APRE only enabled where the register budget allows (no spill).
template<int NT, int KS, int MT, int SLOTS, int APRE>
__device__ __forceinline__ void mmN(const unsigned short* Ab, int EA,
                                    const bf16x8* __restrict__ Wf, int wnb, int KT, int l,
                                    float4v* acc) {
  if constexpr (SLOTS == 2) {
    bf16x8 p0[NT], p1[NT];
    #pragma unroll
    for (int n = 0; n < NT; ++n) {
      p0[n] = Wf[(size_t)((wnb + n) * KT) * 64 + l];
      p1[n] = Wf[(size_t)((wnb + n) * KT + 1) * 64 + l];
    }
    bf16x8 a0[MT], a1[MT];
    if constexpr (APRE) {
      #pragma unroll
      for (int m = 0; m < MT; ++m) {
        a0[m] = ldfrag(Ab, EA, m * 16, 0, l);
        a1[m] = ldfrag(Ab, EA, m * 16, 32, l);
      }
    }
    #pragma unroll 1
    for (int kt = 0; kt < KS; kt += 2) {
      {
        if constexpr (!APRE) {
          #pragma unroll
          for (int m = 0; m < MT; ++m) a0[m] = ldfrag(Ab, EA, m * 16, kt * 32, l);
        }
        #pragma unroll
        for (int n = 0; n < NT; ++n) {
          #pragma unroll
          for (int m = 0; m < MT; ++m)
            acc[m * NT + n] = __builtin_amdgcn_mfma_f32_16x16x32_bf16(a0[m], p0[n], acc[m * NT + n], 0, 0, 0);
        }
        if (kt + 2 < KS) {
          #pragma unroll
          for (int n = 0; n < NT; ++n)
            p0[n] = Wf[(size_t)((wnb + n) * KT + kt + 2) * 64 + l];
          if constexpr (APRE) {
            #pragma unroll
            for (int m = 0; m < MT; ++m) a0[m] = ldfrag(Ab, EA, m * 16, (kt + 2) * 32, l);
          }
        }
      }
      {
        if constexpr (!APRE) {
          #pragma unroll
          for (int m = 0; m < MT; ++m) a1[m] = ldfrag(Ab, EA, m * 16, (kt + 1) * 32, l);
        }
        #pragma unroll
        for (int n = 0; n < NT; ++n) {
          #pragma unroll
          for (int m = 0; m < MT; ++m)
            acc[m * NT + n] = __builtin_amdgcn_mfma_f32_16x16x32_bf16(a1[m], p1[n], acc[m * NT + n], 0, 0, 0);
        }
        if (kt + 3 < KS) {
          #pragma unroll
          for (int n = 0; n < NT; ++n)
            p1[n] = Wf[(size_t)((wnb + n) * KT + kt + 3) * 64 + l];
          if constexpr (APRE) {
            #pragma unroll
            for (int m = 0; m < MT; ++m) a1[m] = ldfrag(Ab, EA, m * 16, (kt + 3) * 32, l);
          }
        }
      }
    }
  } else {
    bf16x8 bn[NT];
    #pragma unroll
    for (int n = 0; n < NT; ++n) bn[n] = Wf[(size_t)((wnb + n) * KT) * 64 + l];
    #pragma unroll 1
    for (int kt = 0; kt < KS; ++kt) {
      bf16x8 a[MT];
      #pragma unroll
      for (int m = 0; m < MT; ++m) a[m] = ldfrag(Ab, EA, m * 16, kt * 32, l);
      #pragma unroll
      for (int n = 0; n < NT; ++n) {
        #pragma unroll
        for (int m = 0; m < MT; ++m)
          acc[m * NT + n] = __builtin_amdgcn_mfma_f32_16x16x32_bf16(a[m], bn[n], acc[m * NT + n], 0, 0, 0);
      }
      if (kt + 1 < KS) {
        #pragma unroll
        for (int n = 0; n < NT; ++n)
          bn[n] = Wf[(size_t)((wnb + n) * KT + kt + 1) * 64 + l];
      }
    }
  }
}

// LayerNorm over rows {w, w+16, ...} < nrows of sXbuf [64][512] bf16 (swizzled).
// All 16 waves participate regardless of MT.
__device__ __forceinline__ void ln_pass(unsigned short* sXbuf, const float* __restrict__ g,
                                        const float* __restrict__ bb, int w, int l, int nrows) {
  float gv[8], bv[8];
  {
    const float4* g4 = (const float4*)(g + l * 8);
    const float4* b4 = (const float4*)(bb + l * 8);
    float4 a0 = g4[0], a1 = g4[1], c0 = b4[0], c1 = b4[1];
    gv[0] = a0.x; gv[1] = a0.y; gv[2] = a0.z; gv[3] = a0.w;
    gv[4] = a1.x; gv[5] = a1.y; gv[6] = a1.z; gv[7] = a1.w;
    bv[0] = c0.x; bv[1] = c0.y; bv[2] = c0.z; bv[3] = c0.w;
    bv[4] = c1.x; bv[5] = c1.y; bv[6] = c1.z; bv[7] = c1.w;
  }
  #pragma unroll 1
  for (int r = w; r < nrows; r += 16) {
    int e = r * 512 + (((l << 4) ^ ((r & 7) << 4)) >> 1);  // cols l*8..l*8+7
    ushort8v x = *(const ushort8v*)(sXbuf + e);
    float v[8];
    float s = 0.f, s2 = 0.f;
    #pragma unroll
    for (int j = 0; j < 8; ++j) { v[j] = b2f(x[j]); s += v[j]; s2 += v[j] * v[j]; }
    #pragma unroll
    for (int off = 1; off < 64; off <<= 1) { s += __shfl_xor(s, off); s2 += __shfl_xor(s2, off); }
    float mu = s * (1.f / 512.f);
    float var = s2 * (1.f / 512.f) - mu * mu;
    float rstd = rsqrtf(var + 1e-6f);
    ushort8v o;
    #pragma unroll
    for (int j = 0; j < 8; ++j) o[j] = f2b((v[j] - mu) * rstd * gv[j] + bv[j]);
    *(ushort8v*)(sXbuf + e) = o;
  }
}

// Whole per-block pipeline, templated on MT = number of 16-row tiles actually
// containing valid tokens (rows > len never influence the masked-pooled output;
// rows in (len, 16*MT) are zero-filled so all intermediates stay finite).
template<int MT>
__device__ __forceinline__ void body(
    unsigned short* sX, unsigned short* sQ, unsigned short* sK,
    float* sS, unsigned short* sP,
    const float* __restrict__ embed, const int* __restrict__ gidx,
    const float* __restrict__ b1, const float* __restrict__ b2,
    const float* __restrict__ ln1g, const float* __restrict__ ln1b,
    const float* __restrict__ bqkv, const float* __restrict__ bo,
    const float* __restrict__ ln2g, const float* __restrict__ ln2b,
    const unsigned short* __restrict__ w1f, const unsigned short* __restrict__ w2f,
    const unsigned short* __restrict__ wqkvf, const unsigned short* __restrict__ wof,
    float* __restrict__ out, int tid, int w, int l, int b, int len) {

  // Budgets sized so peak live set stays within the 64-VGPR allocation.
  constexpr int S2 = (MT <= 3) ? 2 : 1;        // NT=2 (FF2, Wo) B slots
  constexpr int AP1 = (MT <= 3) ? 1 : 0;       // NT=1 passes: A prefetch
  constexpr int AP2 = (MT <= 2) ? 1 : 0;       // NT=2 passes: A prefetch

  // ---- phase 0: embedding gather -> sX rows [0, 16*MT); zeros beyond len ----
  {
    const int sub = tid >> 7;          // 0..7
    const int c0 = (tid & 127) << 2;   // col base
    #pragma unroll 2
    for (int it = 0; it < 2 * MT; ++it) {
      int r = it * 8 + sub;
      float4 v = make_float4(0.f, 0.f, 0.f, 0.f);
      if (r <= len) {
        int row = gidx[b * K_S + r];
        v = *(const float4*)(embed + (size_t)row * K_D + c0);
      }
      ushort4v o;
      o[0] = f2b(v.x); o[1] = f2b(v.y); o[2] = f2b(v.z); o[3] = f2b(v.w);
      *(ushort4v*)(sX + r * 512 + (((c0 << 1) ^ ((r & 7) << 4)) >> 1)) = o;
    }
  }
  __syncthreads();

  // ---- phase 1: F = relu(X @ W1 + b1) -> sQ rows < 16*MT ----
  {
    float4v acc[MT];
    #pragma unroll
    for (int i = 0; i < MT; ++i) acc[i] = (float4v){0.f, 0.f, 0.f, 0.f};
    mmN<1, 16, MT, 2, AP1>(sX, 512, (const bf16x8*)w1f, w, 16, l, acc);
    int col = w * 16 + (l & 15);
    float bias = b1[col];
    #pragma unroll
    for (int m = 0; m < MT; ++m) {
      int r0 = m * 16 + ((l >> 4) << 2);
      #pragma unroll
      for (int j = 0; j < 4; ++j) {
        int r = r0 + j;
        float v = fmaxf(acc[m][j] + bias, 0.f);
        sQ[r * 256 + (((col << 1) ^ ((r & 7) << 4)) >> 1)] = f2b(v);
      }
    }
  }
  __syncthreads();

  // ---- phase 2: FF2 = F @ W2 + b2 + X -> sX; then LN1 (rows < 16*MT) ----
  {
    float4v acc[2 * MT];
    #pragma unroll
    for (int i = 0; i < 2 * MT; ++i) acc[i] = (float4v){0.f, 0.f, 0.f, 0.f};
    mmN<2, 8, MT, S2, AP2>(sQ, 256, (const bf16x8*)w2f, w * 2, 8, l, acc);
    #pragma unroll
    for (int n = 0; n < 2; ++n) {
      int col = (w * 2 + n) * 16 + (l & 15);
      float bias = b2[col];
      #pragma unroll
      for (int m = 0; m < MT; ++m) {
        int r0 = m * 16 + ((l >> 4) << 2);
        #pragma unroll
        for (int j = 0; j < 4; ++j) {
          int r = r0 + j;
          int e = r * 512 + (((col << 1) ^ ((r & 7) << 4)) >> 1);
          float v = acc[m * 2 + n][j] + bias + b2f(sX[e]);
          sX[e] = f2b(v);
        }
      }
    }
  }
  __syncthreads();
  ln_pass(sX, ln1g, ln1b, w, l, 16 * MT);
  __syncthreads();

  // ---- phase 3a: Q,K = FF @ Wqkv[:, :512] + bias (one A-pass) ----
  {
    const bf16x8* Wf = (const bf16x8*)wqkvf;
    float4v accQ[MT], accK[MT];
    #pragma unroll
    for (int i = 0; i < MT; ++i) {
      accQ[i] = (float4v){0.f, 0.f, 0.f, 0.f};
      accK[i] = (float4v){0.f, 0.f, 0.f, 0.f};
    }
    const size_t baseQ = (size_t)(w) * 16 * 64 + l;
    const size_t baseK = (size_t)(16 + w) * 16 * 64 + l;
    if constexpr (MT <= 2) {
      // two-slot B AND A, unroll-2, consume-then-refill (no copies)
      bf16x8 q0 = Wf[baseQ],       k0 = Wf[baseK];
      bf16x8 q1 = Wf[baseQ + 64],  k1 = Wf[baseK + 64];
      bf16x8 a0[MT], a1[MT];
      #pragma unroll
      for (int m = 0; m < MT; ++m) {
        a0[m] = ldfrag(sX, 512, m * 16, 0, l);
        a1[m] = ldfrag(sX, 512, m * 16, 32, l);
      }
      #pragma unroll 1
      for (int kt = 0; kt < 16; kt += 2) {
        {
          #pragma unroll
          for (int m = 0; m < MT; ++m) accQ[m] = __builtin_amdgcn_mfma_f32_16x16x32_bf16(a0[m], q0, accQ[m], 0, 0, 0);
          #pragma unroll
          for (int m = 0; m < MT; ++m) accK[m] = __builtin_amdgcn_mfma_f32_16x16x32_bf16(a0[m], k0, accK[m], 0, 0, 0);
          if (kt + 2 < 16) {
            q0 = Wf[baseQ + (size_t)(kt + 2) * 64];
            k0 = Wf[baseK + (size_t)(kt + 2) * 64];
            #pragma unroll
            for (int m = 0; m < MT; ++m) a0[m] = ldfrag(sX, 512, m * 16, (kt + 2) * 32, l);
          }
        }
        {
          #pragma unroll
          for (int m = 0; m < MT; ++m) accQ[m] = __builtin_amdgcn_mfma_f32_16x16x32_bf16(a1[m], q1, accQ[m], 0, 0, 0);
          #pragma unroll
          for (int m = 0; m < MT; ++m) accK[m] = __builtin_amdgcn_mfma_f32_16x16x32_bf16(a1[m], k1, accK[m], 0, 0, 0);
          if (kt + 3 < 16) {
            q1 = Wf[baseQ + (size_t)(kt + 3) * 64];
            k1 = Wf[baseK + (size_t)(kt + 3) * 64];
            #pragma unroll
            for (int m = 0; m < MT; ++m) a1[m] = ldfrag(sX, 512, m * 16, (kt + 3) * 32, l);
          }
        }
      }
    } else {
      bf16x8 q0 = Wf[baseQ], k0 = Wf[baseK];
      #pragma unroll 1
      for (int kt = 0; kt < 16; ++kt) {
        bf16x8 a[MT];
        #pragma unroll
        for (int m = 0; m < MT; ++m) a[m] = ldfrag(sX, 512, m * 16, kt * 32, l);
        #pragma unroll
        for (int m = 0; m < MT; ++m) accQ[m] = __builtin_amdgcn_mfma_f32_16x16x32_bf16(a[m], q0, accQ[m], 0, 0, 0);
        #pragma unroll
        for (int m = 0; m < MT; ++m) accK[m] = __builtin_amdgcn_mfma_f32_16x16x32_bf16(a[m], k0, accK[m], 0, 0, 0);
        if (kt + 1 < 16) {
          q0 = Wf[baseQ + (size_t)(kt + 1) * 64];
          k0 = Wf[baseK + (size_t)(kt + 1) * 64];
        }
      }
    }
    const float qscale = 0.044194173824159216f;  // 1/sqrt(512)
    int col = w * 16 + (l & 15);
    float biasQ = bqkv[col];
    float biasK = bqkv[256 + col];
    #pragma unroll
    for (int m = 0; m < MT; ++m) {
      int r0 = m * 16 + ((l >> 4) << 2);
      #pragma unroll
      for (int j = 0; j < 4; ++j) {
        int r = r0 + j;
        sQ[r * 256 + (((col << 1) ^ ((r & 7) << 4)) >> 1)] = f2b((accQ[m][j] + biasQ) * qscale);
        sK[r * 256 + (((col << 1) ^ ((r & 7) << 4)) >> 1)] = f2b(accK[m][j] + biasK);
      }
    }
  }
  __syncthreads();

  // ---- phase 4 (score-waves) overlapped with phase 3b (V pass, all waves) ----
  if ((w >> 2) < MT) {
    float4v acc = (float4v){0.f, 0.f, 0.f, 0.f};
    int n0 = (w & 3) * 16;
    int m0 = (w >> 2) * 16;
    bf16x8 b0 = ldfrag(sK, 256, n0, 0, l),  aq0 = ldfrag(sQ, 256, m0, 0, l);
    bf16x8 b1 = ldfrag(sK, 256, n0, 32, l), aq1 = ldfrag(sQ, 256, m0, 32, l);
    #pragma unroll 1
    for (int kt = 0; kt < 8; kt += 2) {
      acc = __builtin_amdgcn_mfma_f32_16x16x32_bf16(aq0, b0, acc, 0, 0, 0);
      if (kt + 2 < 8) {
        b0 = ldfrag(sK, 256, n0, (kt + 2) * 32, l);
        aq0 = ldfrag(sQ, 256, m0, (kt + 2) * 32, l);
      }
      acc = __builtin_amdgcn_mfma_f32_16x16x32_bf16(aq1, b1, acc, 0, 0, 0);
      if (kt + 3 < 8) {
        b1 = ldfrag(sK, 256, n0, (kt + 3) * 32, l);
        aq1 = ldfrag(sQ, 256, m0, (kt + 3) * 32, l);
      }
    }
    int col = n0 + (l & 15);
    int r0 = m0 + ((l >> 4) << 2);
    #pragma unroll
    for (int j = 0; j < 4; ++j) {
      int r = r0 + j;
      sS[r * 64 + (((col << 2) ^ ((r & 7) << 4)) >> 2)] = acc[j];
    }
  }
  // V = FF @ Wqkv[:, 512:]; V stays in regs until phase 5
  float4v accV[MT];
  {
    #pragma unroll
    for (int i = 0; i < MT; ++i) accV[i] = (float4v){0.f, 0.f, 0.f, 0.f};
    mmN<1, 16, MT, 2, AP1>(sX, 512, (const bf16x8*)wqkvf, 32 + w, 16, l, accV);
  }
  __syncthreads();

  // ---- phase 5: masked softmax (rows spread over all waves) -> sP; V^T -> sK ----
  {
    const bool valid = (l <= len);
    #pragma unroll 1
    for (int r = w; r < 16 * MT; r += 16) {
      float s = valid ? sS[r * 64 + (((l << 2) ^ ((r & 7) << 4)) >> 2)] : -1e30f;
      float mx = s;
      #pragma unroll
      for (int off = 1; off < 64; off <<= 1) mx = fmaxf(mx, __shfl_xor(mx, off));
      float p = valid ? __expf(s - mx) : 0.f;
      float sum = p;
      #pragma unroll
      for (int off = 1; off < 64; off <<= 1) sum += __shfl_xor(sum, off);
      sP[r * 64 + (((l << 1) ^ ((r & 7) << 4)) >> 1)] = f2b(p / sum);
    }
    // V^T write (sK free after the phase-4 reads): feature c, rows r0..r0+3.
    // k-rows >= 16*MT zero-filled: P there is 0, but 0 * uninit-LDS-NaN = NaN.
    int c = w * 16 + (l & 15);
    float biasV = bqkv[512 + c];
    #pragma unroll
    for (int m = 0; m < MT; ++m) {
      int r0 = m * 16 + ((l >> 4) << 2);
      ushort4v o;
      #pragma unroll
      for (int j = 0; j < 4; ++j) o[j] = f2b(accV[m][j] + biasV);
      *(ushort4v*)(sK + c * 64 + (((r0 << 1) ^ ((c & 7) << 4)) >> 1)) = o;
    }
    #pragma unroll
    for (int m = MT; m < 4; ++m) {
      int r0 = m * 16 + ((l >> 4) << 2);
      ushort4v o; o[0] = 0; o[1] = 0; o[2] = 0; o[3] = 0;
      *(ushort4v*)(sK + c * 64 + (((r0 << 1) ^ ((c & 7) << 4)) >> 1)) = o;
    }
  }
  __syncthreads();

  // ---- phase 7: ctx = P @ V -> sQ rows < 16*MT ----
  {
    float4v acc[MT];
    #pragma unroll
    for (int i = 0; i < MT; ++i) acc[i] = (float4v){0.f, 0.f, 0.f, 0.f};
    #pragma unroll
    for (int kt = 0; kt < 2; ++kt) {
      bf16x8 bfr = ldfrag(sK, 64, w * 16, kt * 32, l);
      #pragma unroll
      for (int m = 0; m < MT; ++m) {
        bf16x8 a = ldfrag(sP, 64, m * 16, kt * 32, l);
        acc[m] = __builtin_amdgcn_mfma_f32_16x16x32_bf16(a, bfr, acc[m], 0, 0, 0);
      }
    }
    int col = w * 16 + (l & 15);
    #pragma unroll
    for (int m = 0; m < MT; ++m) {
      int r0 = m * 16 + ((l >> 4) << 2);
      #pragma unroll
      for (int j = 0; j < 4; ++j) {
        int r = r0 + j;
        sQ[r * 256 + (((col << 1) ^ ((r & 7) << 4)) >> 1)] = f2b(acc[m][j]);
      }
    }
  }
  __syncthreads();

  // ---- phase 8: O = ctx @ Wo + bo + FF -> sX; LN2 (rows < 16*MT) ----
  {
    float4v acc[2 * MT];
    #pragma unroll
    for (int i = 0; i < 2 * MT; ++i) acc[i] = (float4v){0.f, 0.f, 0.f, 0.f};
    mmN<2, 8, MT, S2, AP2>(sQ, 256, (const bf16x8*)wof, w * 2, 8, l, acc);
    #pragma unroll
    for (int n = 0; n < 2; ++n) {
      int col = (w * 2 + n) * 16 + (l & 15);
      float bias = bo[col];
      #pragma unroll
      for (int m = 0; m < MT; ++m) {
        int r0 = m * 16 + ((l >> 4) << 2);
        #pragma unroll
        for (int j = 0; j < 4; ++j) {
          int r = r0 + j;
          int e = r * 512 + (((col << 1) ^ ((r & 7) << 4)) >> 1);
          float v = acc[m * 2 + n][j] + bias + b2f(sX[e]);
          sX[e] = f2b(v);
        }
      }
    }
  }
  __syncthreads();
  ln_pass(sX, ln2g, ln2b, w, l, 16 * MT);
  __syncthreads();

  // ---- phase 9: masked mean pool -> out[b][512]; two row-halves via sS scratch ----
  {
    int col = tid & 511;
    int half = tid >> 9;  // 0 or 1
    float sum = 0.f;
    for (int s = half; s <= len; s += 2)
      sum += b2f(sX[s * 512 + (((col << 1) ^ ((s & 7) << 4)) >> 1)]);
    if (half) sS[col] = sum;
    __syncthreads();
    if (!half) out[(size_t)b * K_D + col] = (sum + sS[col]) / (float)(len + 1);
  }
}

__global__ __launch_bounds__(1024, 4)
void fused_block(
    const float* __restrict__ embed, const int* __restrict__ gidx,
    const int* __restrict__ lengths,
    const float* __restrict__ b1, const float* __restrict__ b2,
    const float* __restrict__ ln1g, const float* __restrict__ ln1b,
    const float* __restrict__ bqkv, const float* __restrict__ bo,
    const float* __restrict__ ln2g, const float* __restrict__ ln2b,
    const unsigned short* __restrict__ w1f, const unsigned short* __restrict__ w2f,
    const unsigned short* __restrict__ wqkvf, const unsigned short* __restrict__ wof,
    float* __restrict__ out) {
  __shared__ unsigned short sX[64 * 512];  // X, then FF(post-LN1), then LN2 out
  __shared__ unsigned short sQ[64 * 256];  // F, then Q, then ctx
  __shared__ unsigned short sK[64 * 256];  // K, then V^T [256][64]
  __shared__ float sS[64 * 64];            // raw scores fp32; later pool scratch
  __shared__ unsigned short sP[64 * 64];   // probs bf16

  const int tid = (int)threadIdx.x;
  const int w = tid >> 6;   // 0..15
  const int l = tid & 63;
  const int b = (int)blockIdx.x;
  const int len = lengths[b];
  const int mt = (len + 16) >> 4;  // ceil((len+1)/16), 1..4

  switch (mt) {
    case 1: body<1>(sX, sQ, sK, sS, sP, embed, gidx, b1, b2, ln1g, ln1b, bqkv, bo,
                    ln2g, ln2b, w1f, w2f, wqkvf, wof, out, tid, w, l, b, len); break;
    case 2: body<2>(sX, sQ, sK, sS, sP, embed, gidx, b1, b2, ln1g, ln1b, bqkv, bo,
                    ln2g, ln2b, w1f, w2f, wqkvf, wof, out, tid, w, l, b, len); break;
    case 3: body<3>(sX, sQ, sK, sS, sP, embed, gidx, b1, b2, ln1g, ln1b, bqkv, bo,
                    ln2g, ln2b, w1f, w2f, wqkvf, wof, out, tid, w, l, b, len); break;
    default: body<4>(sX, sQ, sK, sS, sP, embed, gidx, b1, b2, ln1g, ln1b, bqkv, bo,
                     ln2g, ln2b, w1f, w2f, wqkvf, wof, out, tid, w, l, b, len); break;
  }
}

extern "C" void kernel_launch(void* const* d_in, const int* in_sizes, int n_in,
                              void* d_out, int out_size, void* d_ws, size_t ws_size,
                              hipStream_t stream) {
  (void)in_sizes; (void)n_in; (void)out_size; (void)ws_size;
  const float* embed = (const float*)d_in[0];
  const int* idx = (const int*)d_in[1];
  const int* lengths = (const int*)d_in[2];
  const float* W1 = (const float*)d_in[3];
  const float* b1 = (const float*)d_in[4];
  const float* W2 = (const float*)d_in[5];
  const float* b2 = (const float*)d_in[6];
  const float* ln1g = (const float*)d_in[7];
  const float* ln1b = (const float*)d_in[8];
  const float* Wqkv = (const float*)d_in[9];
  const float* bqkv = (const float*)d_in[10];
  const float* Wo = (const float*)d_in[11];
  const float* bo = (const float*)d_in[12];
  const float* ln2g = (const float*)d_in[13];
  const float* ln2b = (const float*)d_in[14];

  unsigned short* ws = (unsigned short*)d_ws;
  unsigned short* w1f = ws;                 // 16 nt * 16 kt * 512  = 131072 bf16
  unsigned short* w2f = ws + 131072;        // 32 nt *  8 kt * 512  = 131072
  unsigned short* wqkvf = ws + 262144;      // 48 nt * 16 kt * 512  = 393216
  unsigned short* wof = ws + 655360;        // 32 nt *  8 kt * 512  = 131072

  prep_weights<<<64, 256, 0, stream>>>(W1, w1f, 512, 256);
  prep_weights<<<64, 256, 0, stream>>>(W2, w2f, 256, 512);
  prep_weights<<<192, 256, 0, stream>>>(Wqkv, wqkvf, 512, 768);
  prep_weights<<<64, 256, 0, stream>>>(Wo, wof, 256, 512);

  fused_block<<<4096, 1024, 0, stream>>>(embed, idx, lengths, b1, b2, ln1g, ln1b,
                                         bqkv, bo, ln2g, ln2b, w1f, w2f, wqkvf, wof,
                                         (float*)d_out);
}